// Round 7
// baseline (295.105 us; speedup 1.0000x reference)
//
#include <hip/hip_runtime.h>

// Problem constants (from reference): B=32, A=262144, K=131072.
#define A_ELEMS   262144
#define A_SHIFT   18        // log2(A_ELEMS)
#define K_ELEMS   131072

__global__ void zero_ws_kernel(float* ws) {
    // ws[0] = loss sum, ws[1] = mask count. d_ws is poisoned 0xAA each call.
    ws[0] = 0.0f;
    ws[1] = 0.0f;
}

__global__ __launch_bounds__(256) void regloss_main_kernel(
    const float* __restrict__ input,    // (B, 2*K) f32
    const float4* __restrict__ target,  // (B*A) x float4: (x, y, idx, state)
    float* __restrict__ ws,
    long long N)                        // B*A
{
    long long tid    = (long long)blockIdx.x * blockDim.x + threadIdx.x;
    long long stride = (long long)gridDim.x * blockDim.x;

    float loss = 0.0f;
    float cnt  = 0.0f;

    for (long long i = tid; i < N; i += stride) {
        float4 t = target[i];            // coalesced 16B/lane
        if (t.w == 1.0f) {               // mask: state == 1.0 exactly
            int b   = (int)(i >> A_SHIFT);
            int idx = (int)t.z;          // idx stored as exact small float
            idx = min(max(idx, 0), K_ELEMS - 1);
            const float* inb = input + (long long)b * (2 * K_ELEMS);
            float gx = inb[idx];                 // regression[b,0,idx]
            float gy = inb[K_ELEMS + idx];       // regression[b,1,idx]
            float dx = gx - t.x;
            float dy = gy - t.y;
            float adx = fabsf(dx);
            float ady = fabsf(dy);
            loss += (adx < 1.0f) ? 0.5f * dx * dx : adx - 0.5f;
            loss += (ady < 1.0f) ? 0.5f * dy * dy : ady - 0.5f;
            cnt  += 1.0f;
        }
    }

    // Wave-64 butterfly reduce
    #pragma unroll
    for (int off = 32; off > 0; off >>= 1) {
        loss += __shfl_down(loss, off, 64);
        cnt  += __shfl_down(cnt,  off, 64);
    }

    __shared__ float sl[4];
    __shared__ float sc[4];
    int wave = threadIdx.x >> 6;
    int lane = threadIdx.x & 63;
    if (lane == 0) { sl[wave] = loss; sc[wave] = cnt; }
    __syncthreads();
    if (threadIdx.x == 0) {
        float L = sl[0] + sl[1] + sl[2] + sl[3];
        float C = sc[0] + sc[1] + sc[2] + sc[3];
        atomicAdd(&ws[0], L);   // device-scope by default on CDNA
        atomicAdd(&ws[1], C);
    }
}

__global__ void finalize_kernel(const float* __restrict__ ws,
                                float* __restrict__ out) {
    const float POLY_WEIGHT = 1.0f;
    out[0] = ws[0] / fmaxf(1.0f, ws[1]) * POLY_WEIGHT;
}

extern "C" void kernel_launch(void* const* d_in, const int* in_sizes, int n_in,
                              void* d_out, int out_size, void* d_ws, size_t ws_size,
                              hipStream_t stream) {
    const float*  input  = (const float*)d_in[0];        // (B, 2K) f32
    const float4* target = (const float4*)d_in[1];       // (B, A, 4) f32
    float* out = (float*)d_out;
    float* ws  = (float*)d_ws;

    long long N = (long long)in_sizes[1] / 4;            // B*A elements

    zero_ws_kernel<<<1, 1, 0, stream>>>(ws);

    // ~2048 blocks: 8 blocks/CU over 256 CUs; 16 grid-stride iters/thread.
    regloss_main_kernel<<<2048, 256, 0, stream>>>(input, target, ws, N);

    finalize_kernel<<<1, 1, 0, stream>>>(ws, out);
}